// Round 2
// baseline (425.743 us; speedup 1.0000x reference)
//
#include <hip/hip_runtime.h>
#include <cmath>

// Problem constants: S=16384, IN_DIM=1024, D=6400, BINS=20
#define S_DIM 16384
#define K_DIM 1024
#define D_DIM 6400
#define NBINS 20
#define HSTRIDE 21   // shist column stride (pad 20->21: spreads banks)

using half_t = _Float16;
using half8  = __attribute__((ext_vector_type(8))) _Float16;
using f32x4  = __attribute__((ext_vector_type(4))) float;
using f32x16 = __attribute__((ext_vector_type(16))) float;

// ---------------- fp32 -> fp16 convert + d_out zeroing (one launch) -------
__global__ void cvt_f32_f16(const float* __restrict__ a, half_t* __restrict__ da, int n8a,
                            const float* __restrict__ b, half_t* __restrict__ db, int n8b,
                            float4* __restrict__ z, int nz4) {
  int i = blockIdx.x * blockDim.x + threadIdx.x;
  if (i < nz4) z[i] = (float4){0.f, 0.f, 0.f, 0.f};   // histogram accumulator
  const float* s; half_t* d; int idx;
  if (i < n8a) { s = a; d = da; idx = i; }
  else { idx = i - n8a; if (idx >= n8b) return; s = b; d = db; }
  float4 v0 = ((const float4*)s)[idx * 2];
  float4 v1 = ((const float4*)s)[idx * 2 + 1];
  half8 h = { (half_t)v0.x, (half_t)v0.y, (half_t)v0.z, (half_t)v0.w,
              (half_t)v1.x, (half_t)v1.y, (half_t)v1.z, (half_t)v1.w };
  ((half8*)d)[idx] = h;
}

// Raw barrier / counted waitcnt (no compiler vmcnt(0) drain at barriers).
#define VMWAIT(N) __asm__ volatile("s_waitcnt vmcnt(" #N ")" ::: "memory")
#define BAR()     __asm__ volatile("s_barrier" ::: "memory")
#define SP1()     __builtin_amdgcn_s_setprio(1)
#define SP0()     __builtin_amdgcn_s_setprio(0)

#define GLL(SRC, DST) __builtin_amdgcn_global_load_lds(                      \
    (const __attribute__((address_space(1))) void*)(SRC),                    \
    (__attribute__((address_space(3))) void*)(DST), 16, 0, 0)

// ---------------- fused GEMM + histogram, 256x256 tile, 8-wave 4-phase ----
// 512 threads = 8 waves (2M x 4N); per-wave C = 128x64; BK=64; dbuf LDS.
// MFMA core: 32x32x16 f16 (8 MFMA/phase, half the issue slots of 16x16x32).
// Frag layout: A/B row|col = lane&31, k = (lane>>5)*8+j; C/D col = lane&31.
// Phases per K-tile (quadrants of the 4mf x 2nf frag grid):
//   p0: read A(mf01)+B(nf0) [12 ds_read]; stage B.h0(t+1); MFMA Q(0,0)
//   p1: read B(nf1)          [4];        stage B.h1(t+1); MFMA Q(0,1)
//   p2: read A(mf23)         [8];        (no stage);      MFMA Q(1,1)
//   p3: (no reads);  stage A.h0+A.h1(t+2) [4 GLL];        MFMA Q(1,0); VMWAIT(4)
// Staging safety: A(t+2) shares buf[t&1]; all A-reads of buf[t] are drained
// (consumed in-phase) before p2's closing barrier, and the A-stage DMAs are
// issued after it -- this also fixes the round-1 latent race (stage issued in
// the same pre-barrier region as LOAD_A(1) reads of overlapping rows).
// vmcnt: steady state p3 has 12 outstanding (A(t+1)4 + B(t+1)4 + A(t+2)4);
// VMWAIT(4) retires exactly tile t+1 -> resident before its p0 reads; never
// drains to 0 until t=14.
// LDS swizzle: LDS[row][c] = global[row][c ^ (row&7)] (16B chunks, 128B rows)
// via pre-swizzled global source; readers XOR the same -> conflict-free.
// ds_read addressing: 4 per-lane base pointers (pA0/pA1/pB0/pB1, one per
// k-slice); everything else (buf parity, mf/nf offsets) is a compile-time
// ds_read offset: immediate -> no per-phase address VALU.
__global__ __launch_bounds__(512, 2) void gemm_hist256(
    const half_t* __restrict__ xh, const half_t* __restrict__ wh,
    const float* __restrict__ mins, const float* __restrict__ maxs,
    int* __restrict__ ghist)
{
  __shared__ __align__(16) char ldsA[65536];   // 2 bufs x 256 rows x 128 B
  __shared__ __align__(16) char ldsB[65536];
  __shared__ int shist[256 * HSTRIDE];         // 21.5 KB

  const int t    = threadIdx.x;
  const int lane = t & 63;
  const int wv   = t >> 6;
  const int wm   = wv >> 2;          // 0..1
  const int wn   = wv & 3;           // 0..3
  const int l31  = lane & 31;
  const int hi   = lane >> 5;

  // XCD-aware bijective swizzle: 1600 blocks = 8 XCDs x 200
  const int bid = blockIdx.x;
  const int wg  = (bid & 7) * 200 + (bid >> 3);
  const int ct  = wg / 64;                 // 0..24 col-tiles
  const int rt  = wg - ct * 64;            // 0..63 row-tiles
  const int colBase = ct * 256;
  const int rowBase = rt * 256;

  for (int i = t; i < 256 * HSTRIDE; i += 512) shist[i] = 0;

  // histogram params: this lane's 2 columns (col = wn*64 + nf*32 + l31)
  float mn[2], mx[2], inv[2];
  int lcol[2];
#pragma unroll
  for (int nf = 0; nf < 2; ++nf) {
    int lc = wn * 64 + nf * 32 + l31;
    lcol[nf] = lc;
    float a = mins[colBase + lc], b = maxs[colBase + lc];
    mn[nf] = a; mx[nf] = b;
    inv[nf] = (float)NBINS / (b - a);
  }

  // ds_read base pointers (per k-slice of 16): swizzled chunk = (ks*2+hi)^(lane&7)
  const char* pA0 = ldsA + (wm * 128 + l31) * 128 + (((0 * 2 + hi) ^ (lane & 7)) * 16);
  const char* pA1 = ldsA + (wm * 128 + l31) * 128 + (((1 * 2 + hi) ^ (lane & 7)) * 16);
  const char* pB0 = ldsB + (wn * 64  + l31) * 128 + (((0 * 2 + hi) ^ (lane & 7)) * 16);
  const char* pB1 = ldsB + (wn * 64  + l31) * 128 + (((1 * 2 + hi) ^ (lane & 7)) * 16);

  // Staging: thread t owns linear LDS slot t (16B); fetches the global chunk
  // whose swizzled destination is that slot (pre-swizzled source).
  const int r0 = t >> 3;
  const int gOff = r0 * K_DIM + (((t & 7) ^ (r0 & 7)) * 8);   // elements
  const int wvD  = wv * 1024;                                  // uniform LDS base

  // 4 stream pointers, advanced +64 elements per stage call (monotone tau).
  const half_t* aS0 = xh + (size_t)rowBase * K_DIM + gOff;
  const half_t* aS1 = aS0 + 128 * K_DIM;
  const half_t* bS0 = wh + (size_t)colBase * K_DIM + gOff;
  const half_t* bS1 = bS0 + 128 * K_DIM;

#define STA0(PB) { GLL(aS0, ldsA + (PB) + wvD); GLL(aS0 + 64 * K_DIM, ldsA + (PB) + 8192 + wvD); aS0 += 64; }
#define STA1(PB) { GLL(aS1, ldsA + (PB) + 16384 + wvD); GLL(aS1 + 64 * K_DIM, ldsA + (PB) + 24576 + wvD); aS1 += 64; }
#define STB0(PB) { GLL(bS0, ldsB + (PB) + wvD); GLL(bS0 + 64 * K_DIM, ldsB + (PB) + 8192 + wvD); bS0 += 64; }
#define STB1(PB) { GLL(bS1, ldsB + (PB) + 16384 + wvD); GLL(bS1 + 64 * K_DIM, ldsB + (PB) + 24576 + wvD); bS1 += 64; }

  f32x16 acc[4][2];
#pragma unroll
  for (int m = 0; m < 4; ++m)
#pragma unroll
    for (int n = 0; n < 2; ++n)
      acc[m][n] = (f32x16){0.f,0.f,0.f,0.f,0.f,0.f,0.f,0.f,
                           0.f,0.f,0.f,0.f,0.f,0.f,0.f,0.f};

  half8 aF[2][4], bF0[4], bF1[4];

  // prologue: A(0)->buf0, B(0)->buf0, A(1)->buf1 (12 GLL); retire tile 0.
  STA0(0); STA1(0); STB0(0); STB1(0); STA0(32768); STA1(32768);
  VMWAIT(4); BAR();

  // All mf/nf/buf offsets are literal -> fold into ds_read offset: immediates.
#define LOAD_A32(MH, PB)                                                     \
  _Pragma("unroll") for (int m2 = 0; m2 < 2; ++m2) {                         \
    aF[m2][0] = *(const half8*)(pA0 + (PB) + (MH)*8192 + m2*4096);           \
    aF[m2][1] = *(const half8*)(pA0 + (PB) + (MH)*8192 + m2*4096 + 32);      \
    aF[m2][2] = *(const half8*)(pA1 + (PB) + (MH)*8192 + m2*4096);           \
    aF[m2][3] = *(const half8*)(pA1 + (PB) + (MH)*8192 + m2*4096 + 32);      \
  }
  // note: k-slices 0,1 use pA0 (chunks 0^,1^ via +0/+32? no): slice ks uses
  // chunk (ks*2+hi): ks=0 -> pA0, ks=1 -> pA1, ks=2 -> pA0+? -- chunks 4..7
  // are (2*2+hi)= slices 2,3: these are pA0/pA1 XOR 4 chunks. See LOADK below.

#undef LOAD_A32
  // Re-derive cleanly: slice ks chunk index = ks*2 + hi (0..7). Swizzle XORs
  // (lane&7). (ks*2+hi) ^ x  for ks=0..3 differs from ks=0 value by XOR of
  // (ks*2) only when x's bits don't interfere -- not an XOR-translate in
  // general, so keep FOUR per-slice bases: pS[ks] = base + ((ks*2+hi)^x)*16.
  const char* pA2 = ldsA + (wm * 128 + l31) * 128 + (((2 * 2 + hi) ^ (lane & 7)) * 16);
  const char* pA3 = ldsA + (wm * 128 + l31) * 128 + (((3 * 2 + hi) ^ (lane & 7)) * 16);
  const char* pB2 = ldsB + (wn * 64  + l31) * 128 + (((2 * 2 + hi) ^ (lane & 7)) * 16);
  const char* pB3 = ldsB + (wn * 64  + l31) * 128 + (((3 * 2 + hi) ^ (lane & 7)) * 16);

#define LDA(MH, PB)                                                          \
  _Pragma("unroll") for (int m2 = 0; m2 < 2; ++m2) {                         \
    aF[m2][0] = *(const half8*)(pA0 + (PB) + (MH)*8192 + m2*4096);           \
    aF[m2][1] = *(const half8*)(pA1 + (PB) + (MH)*8192 + m2*4096);           \
    aF[m2][2] = *(const half8*)(pA2 + (PB) + (MH)*8192 + m2*4096);           \
    aF[m2][3] = *(const half8*)(pA3 + (PB) + (MH)*8192 + m2*4096);           \
  }
#define LDB(BF, NF, PB)                                                      \
  {                                                                          \
    BF[0] = *(const half8*)(pB0 + (PB) + (NF)*4096);                         \
    BF[1] = *(const half8*)(pB1 + (PB) + (NF)*4096);                         \
    BF[2] = *(const half8*)(pB2 + (PB) + (NF)*4096);                         \
    BF[3] = *(const half8*)(pB3 + (PB) + (NF)*4096);                         \
  }
#define MFMA_Q(MH, NH, BF)                                                   \
  _Pragma("unroll") for (int ks = 0; ks < 4; ++ks)                           \
  _Pragma("unroll") for (int m2 = 0; m2 < 2; ++m2)                           \
    acc[(MH)*2+m2][NH] = __builtin_amdgcn_mfma_f32_32x32x16_f16(             \
        aF[m2][ks], BF[ks], acc[(MH)*2+m2][NH], 0, 0, 0);

#define TILE(PB, S01, S3, VMACT)                                             \
  {                                                                          \
    LDA(0, PB); LDB(bF0, 0, PB);                                             \
    if (S01) STB0((PB) ^ 32768);                                             \
    BAR(); SP1(); MFMA_Q(0, 0, bF0); SP0(); BAR();                           \
    LDB(bF1, 1, PB);                                                         \
    if (S01) STB1((PB) ^ 32768);                                             \
    BAR(); SP1(); MFMA_Q(0, 1, bF1); SP0(); BAR();                           \
    LDA(1, PB);                                                              \
    BAR(); SP1(); MFMA_Q(1, 1, bF1); SP0(); BAR();                           \
    if (S3) { STA0(PB); STA1(PB); }                                          \
    BAR(); SP1(); MFMA_Q(1, 0, bF0); SP0(); VMACT; BAR();                    \
  }

  for (int tt = 0; tt < 14; tt += 2) {
    TILE(0,     1, 1, VMWAIT(4));
    TILE(32768, 1, 1, VMWAIT(4));
  }
  TILE(0,     1, 0, VMWAIT(0));   // t=14: stage B(15); drain pipeline
  TILE(32768, 0, 0, (void)0);     // t=15: compute only

  // Epilogue: bin this block's 256x256 projections (128 values/thread).
  // torch.histc semantics: count iff min<=v<=max; v==max -> last bin.
#pragma unroll
  for (int nf = 0; nf < 2; ++nf) {
    const float a = mn[nf], b = mx[nf], sc = inv[nf];
    int* colHist = &shist[lcol[nf] * HSTRIDE];
#pragma unroll
    for (int mf = 0; mf < 4; ++mf) {
#pragma unroll
      for (int r = 0; r < 16; ++r) {
        float v = acc[mf][nf][r];
        if (v >= a && v <= b) {
          int bin = (int)((v - a) * sc);          // (v-a)>=0 -> trunc==floor
          bin = bin > NBINS - 1 ? NBINS - 1 : bin;
          atomicAdd(&colHist[bin], 1);
        }
      }
    }
  }
  __syncthreads();
  for (int i = t; i < 256 * NBINS; i += 512) {
    int col = i / NBINS, bin = i - col * NBINS;
    int v = shist[col * HSTRIDE + bin];
    if (v) atomicAdd(&ghist[colBase * NBINS + i], v);
  }
}

// ---------------- fallback (no workspace): fp32-staged 128x128 tile -------
__global__ __launch_bounds__(256) void gemm_hist_fb(
    const float* __restrict__ xf, const float* __restrict__ wf,
    const float* __restrict__ mins, const float* __restrict__ maxs,
    int* __restrict__ ghist)
{
  __shared__ __align__(16) half_t ldsA[4096];
  __shared__ __align__(16) half_t ldsB[4096];
  __shared__ int shist[128 * HSTRIDE];

  const int t     = threadIdx.x;
  const int lane  = t & 63;
  const int wv    = t >> 6;
  const int waveM = wv >> 1;
  const int waveN = wv & 1;
  const int l16   = lane & 15;
  const int quad  = lane >> 4;
  const int colBase = blockIdx.x * 128;

  for (int i = t; i < 128 * HSTRIDE; i += 256) shist[i] = 0;

  float mn[4], mx[4], inv[4];
  int lcol[4];
#pragma unroll
  for (int nt = 0; nt < 4; ++nt) {
    int lc = waveN * 64 + nt * 16 + l16;
    lcol[nt] = lc;
    float a = mins[colBase + lc], b = maxs[colBase + lc];
    mn[nt] = a; mx[nt] = b;
    inv[nt] = (float)NBINS / (b - a);
  }

  int aOff[4], bOff[4];
#pragma unroll
  for (int mt = 0; mt < 4; ++mt) {
    int m = waveM * 64 + mt * 16 + l16;
    aOff[mt] = (m * 4 + (quad ^ ((m >> 1) & 3))) * 8;
  }
#pragma unroll
  for (int nt = 0; nt < 4; ++nt) {
    int n = waveN * 64 + nt * 16 + l16;
    bOff[nt] = (n * 4 + (quad ^ ((n >> 1) & 3))) * 8;
  }

  for (int rt = blockIdx.y; rt < S_DIM / 128; rt += gridDim.y) {
    const int rowBase = rt * 128;
    f32x4 acc[4][4];
#pragma unroll
    for (int mt = 0; mt < 4; ++mt)
#pragma unroll
      for (int nt = 0; nt < 4; ++nt) acc[mt][nt] = (f32x4){0.f, 0.f, 0.f, 0.f};

    for (int kt = 0; kt < K_DIM; kt += 32) {
      __syncthreads();
#pragma unroll
      for (int i = 0; i < 2; ++i) {
        const int seg = t + i * 256;
        const int row = seg >> 2;
        const int kch = (seg & 3) ^ ((row >> 1) & 3);
        const float* ga = xf + (size_t)(rowBase + row) * K_DIM + kt + kch * 8;
        float4 v0 = ((const float4*)ga)[0];
        float4 v1 = ((const float4*)ga)[1];
        half8 h = { (half_t)v0.x, (half_t)v0.y, (half_t)v0.z, (half_t)v0.w,
                    (half_t)v1.x, (half_t)v1.y, (half_t)v1.z, (half_t)v1.w };
        *(half8*)&ldsA[seg * 8] = h;
        const float* gb = wf + (size_t)(colBase + row) * K_DIM + kt + kch * 8;
        float4 u0 = ((const float4*)gb)[0];
        float4 u1 = ((const float4*)gb)[1];
        half8 g = { (half_t)u0.x, (half_t)u0.y, (half_t)u0.z, (half_t)u0.w,
                    (half_t)u1.x, (half_t)u1.y, (half_t)u1.z, (half_t)u1.w };
        *(half8*)&ldsB[seg * 8] = g;
      }
      __syncthreads();
      {
        half8 aFf[4], bFf[4];
#pragma unroll
        for (int mt = 0; mt < 4; ++mt) aFf[mt] = *(const half8*)&ldsA[aOff[mt]];
#pragma unroll
        for (int nt = 0; nt < 4; ++nt) bFf[nt] = *(const half8*)&ldsB[bOff[nt]];
#pragma unroll
        for (int mt = 0; mt < 4; ++mt)
#pragma unroll
          for (int nt = 0; nt < 4; ++nt)
            acc[mt][nt] = __builtin_amdgcn_mfma_f32_16x16x32_f16(
                aFf[mt], bFf[nt], acc[mt][nt], 0, 0, 0);
      }
    }

#pragma unroll
    for (int nt = 0; nt < 4; ++nt) {
      const float a = mn[nt], b = mx[nt], sc = inv[nt];
      int* colHist = &shist[lcol[nt] * HSTRIDE];
#pragma unroll
      for (int mt = 0; mt < 4; ++mt) {
#pragma unroll
        for (int r = 0; r < 4; ++r) {
          float v = acc[mt][nt][r];
          if (v >= a && v <= b) {
            int bin = (int)((v - a) * sc);
            bin = bin > NBINS - 1 ? NBINS - 1 : bin;
            atomicAdd(&colHist[bin], 1);
          }
        }
      }
    }
  }

  __syncthreads();
  for (int i = t; i < 128 * NBINS; i += 256) {
    int col = i / NBINS, bin = i - col * NBINS;
    int v = shist[col * HSTRIDE + bin];
    if (v) atomicAdd(&ghist[colBase * NBINS + i], v);
  }
}

// ---------------- L2 normalize per group of 20 bins (in place) ------------
__global__ void normalize_kernel(const int* __restrict__ hist, float* __restrict__ out) {
  int g = blockIdx.x * blockDim.x + threadIdx.x;
  if (g >= D_DIM) return;
  const int base = g * NBINS;
  float v[NBINS];
  float ss = 0.f;
#pragma unroll
  for (int i = 0; i < NBINS; ++i) { v[i] = (float)hist[base + i]; ss += v[i] * v[i]; }
  float sc = 1.0f / fmaxf(sqrtf(ss), 1e-12f);
#pragma unroll
  for (int i = 0; i < NBINS; ++i) out[base + i] = v[i] * sc;
}

extern "C" void kernel_launch(void* const* d_in, const int* in_sizes, int n_in,
                              void* d_out, int out_size, void* d_ws, size_t ws_size,
                              hipStream_t stream) {
  const float* x    = (const float*)d_in[0];
  const float* W    = (const float*)d_in[1];
  const float* mins = (const float*)d_in[2];
  const float* maxs = (const float*)d_in[3];
  float* out = (float*)d_out;

  const size_t xh_elems = (size_t)S_DIM * K_DIM;
  const size_t wh_elems = (size_t)D_DIM * K_DIM;
  const size_t need = (xh_elems + wh_elems) * sizeof(half_t);

  if (ws_size >= need) {
    half_t* xh = (half_t*)d_ws;
    half_t* wh = xh + xh_elems;
    int n8x = (int)(xh_elems / 8), n8w = (int)(wh_elems / 8);
    int tot = n8x + n8w;
    // cvt also zeroes d_out (re-poisoned 0xAA between runs)
    cvt_f32_f16<<<(tot + 255) / 256, 256, 0, stream>>>(
        x, xh, n8x, W, wh, n8w, (float4*)d_out, out_size / 4);
    gemm_hist256<<<dim3(1600), 512, 0, stream>>>(xh, wh, mins, maxs, (int*)d_out);
  } else {
    hipMemsetAsync(d_out, 0, (size_t)out_size * sizeof(float), stream);
    gemm_hist_fb<<<dim3(D_DIM / 128, 64), 256, 0, stream>>>(
        x, W, mins, maxs, (int*)d_out);
  }

  normalize_kernel<<<(D_DIM + 255) / 256, 256, 0, stream>>>((int*)d_out, out);
}

// Round 3
// 375.101 us; speedup vs baseline: 1.1350x; 1.1350x over previous
//
#include <hip/hip_runtime.h>
#include <cmath>

// Problem constants: S=16384, IN_DIM=1024, D=6400, BINS=20
#define S_DIM 16384
#define K_DIM 1024
#define D_DIM 6400
#define NBINS 20
#define HSTRIDE 21   // shist column stride (pad 20->21: spreads banks)

using half_t = _Float16;
using half8  = __attribute__((ext_vector_type(8))) _Float16;
using f32x4  = __attribute__((ext_vector_type(4))) float;

// ---------------- fp32 -> fp16 convert + d_out zeroing (one launch) -------
__global__ void cvt_f32_f16(const float* __restrict__ a, half_t* __restrict__ da, int n8a,
                            const float* __restrict__ b, half_t* __restrict__ db, int n8b,
                            float4* __restrict__ z, int nz4) {
  int i = blockIdx.x * blockDim.x + threadIdx.x;
  if (i < nz4) z[i] = (float4){0.f, 0.f, 0.f, 0.f};   // histogram accumulator
  const float* s; half_t* d; int idx;
  if (i < n8a) { s = a; d = da; idx = i; }
  else { idx = i - n8a; if (idx >= n8b) return; s = b; d = db; }
  float4 v0 = ((const float4*)s)[idx * 2];
  float4 v1 = ((const float4*)s)[idx * 2 + 1];
  half8 h = { (half_t)v0.x, (half_t)v0.y, (half_t)v0.z, (half_t)v0.w,
              (half_t)v1.x, (half_t)v1.y, (half_t)v1.z, (half_t)v1.w };
  ((half8*)d)[idx] = h;
}

// Raw barrier / counted waitcnt (no compiler vmcnt(0) drain at barriers).
#define VMWAIT(N) __asm__ volatile("s_waitcnt vmcnt(" #N ")" ::: "memory")
#define BAR()     __asm__ volatile("s_barrier" ::: "memory")
#define SP1()     __builtin_amdgcn_s_setprio(1)
#define SP0()     __builtin_amdgcn_s_setprio(0)

#define GLL(SRC, DST) __builtin_amdgcn_global_load_lds(                      \
    (const __attribute__((address_space(1))) void*)(SRC),                    \
    (__attribute__((address_space(3))) void*)(DST), 16, 0, 0)

// ---------------- fused GEMM + histogram, 256x256, 8-wave, pipelined ------
// 512 threads = 8 waves (2M x 4N); per-wave C = 128x64; BK=64; dbuf LDS.
// MFMA core: 16x16x32 f16 (round-1 proven conflict-free read pattern).
// Quadrant order per tile: Q00(aLo,B0) Q01(aLo,B1) Q11(aHi,B1) Q10(aHi,B0).
// One-phase read-ahead using fragment liveness (ZERO extra VGPRs):
//   P0: read B1<-b(t,1)      [B1 dead in P0]        ; MFMA Q00
//   P1: read aHi<-a(t,hi)    [aHi dead P0-P1]       ; MFMA Q01 ; VMW(4); BAR
//   P2: read aLo<-a(t+1,lo)  [aLo dead after P1]    ; MFMA Q11 ; VMW(0); BAR
//   P3: stage {A,B}(t+2)->buf[t]; MFMA Q10; read B0<-b(t+1,0) [after Q10]
// MFMA always consumes frags read >=1 phase earlier -> LDS pipe overlaps
// the MFMA pipe instead of barrier-serializing with it (round-1's 8-barrier
// lockstep made per-tile time ~ LDS + MFMA instead of max(LDS, MFMA)).
// Sync: 2 barriers + 2 vmcnt per tile.
//  - VMWAIT(4)@P1end: in-flight = {A,B}(t+1) (8, issued t-1 P3, A first);
//    retires A(t+1) -> P2's aLo read safe after BAR.
//  - VMWAIT(0)@P2end: in-flight = B(t+1) (4, issued 4 phases earlier ->
//    latency fully covered, no real drain stall); publishes B for P3's read.
//  - Staging WAR: {A,B}(t+2) overwrite buf[t]; every wave's reads of buf[t]
//    (B1@P0 consumed by Q01 pre-P1end-BAR; aHi@P1 consumed by Q11 pre-
//    P2end-BAR; aLo/B0 consumed even earlier) complete before any wave
//    passes P2end BAR and issues the P3 stage. (Fixes round-1 latent race.)
// LDS swizzle: LDS[row][c] = global[row][c ^ (row&7)] (16B chunks, 128B rows)
// via pre-swizzled global source; readers XOR the same -> conflict-free
// (round-1 measured: GEMM contributes ~0 to SQ_LDS_BANK_CONFLICT).
__global__ __launch_bounds__(512, 2) void gemm_hist256(
    const half_t* __restrict__ xh, const half_t* __restrict__ wh,
    const float* __restrict__ mins, const float* __restrict__ maxs,
    int* __restrict__ ghist)
{
  __shared__ __align__(16) char ldsA[65536];   // 2 bufs x 256 rows x 128 B
  __shared__ __align__(16) char ldsB[65536];
  __shared__ int shist[256 * HSTRIDE];         // 21.5 KB

  const int t    = threadIdx.x;
  const int lane = t & 63;
  const int wv   = t >> 6;
  const int wm   = wv >> 2;          // 0..1
  const int wn   = wv & 3;           // 0..3
  const int l16  = lane & 15;
  const int quad = lane >> 4;

  // XCD-aware bijective swizzle: 1600 blocks = 8 XCDs x 200
  const int bid = blockIdx.x;
  const int wg  = (bid & 7) * 200 + (bid >> 3);
  const int ct  = wg / 64;                 // 0..24 col-tiles
  const int rt  = wg - ct * 64;            // 0..63 row-tiles
  const int colBase = ct * 256;
  const int rowBase = rt * 256;

  for (int i = t; i < 256 * HSTRIDE; i += 512) shist[i] = 0;

  // ds_read base pointers per k-slice (ks=0,1): chunk = (ks*4+quad)^(lane&7).
  // Row of every fragment read = (...*16 + l16) -> row&7 == lane&7: matches
  // the staging swizzle key.  mf/nf/buf offsets fold into offset: immediates.
  const char* pA[2];
  const char* pB[2];
#pragma unroll
  for (int ks = 0; ks < 2; ++ks) {
    int ch = ((ks * 4 + quad) ^ (lane & 7)) * 16;
    pA[ks] = ldsA + (wm * 128 + l16) * 128 + ch;
    pB[ks] = ldsB + (wn * 64 + l16) * 128 + ch;
  }

  // Staging: thread t owns linear LDS slot t*16B per 8KB region; fetches the
  // global chunk whose swizzled destination is that slot.
  const int r0 = t >> 3;
  const int gOff = r0 * K_DIM + (((t & 7) ^ (r0 & 7)) * 8);   // elements
  const int wvD  = wv * 1024;   // wave-uniform LDS base (HW adds lane*16)

  const half_t* aS = xh + (size_t)rowBase * K_DIM + gOff;   // advances +64/tile
  const half_t* bS = wh + (size_t)colBase * K_DIM + gOff;

#define STA(PB) {                                                            \
    GLL(aS,                 ldsA + (PB) + wvD);                              \
    GLL(aS +  64 * K_DIM,   ldsA + (PB) +  8192 + wvD);                      \
    GLL(aS + 128 * K_DIM,   ldsA + (PB) + 16384 + wvD);                      \
    GLL(aS + 192 * K_DIM,   ldsA + (PB) + 24576 + wvD);                      \
    aS += 64; }
#define STB(PB) {                                                            \
    GLL(bS,                 ldsB + (PB) + wvD);                              \
    GLL(bS +  64 * K_DIM,   ldsB + (PB) +  8192 + wvD);                      \
    GLL(bS + 128 * K_DIM,   ldsB + (PB) + 16384 + wvD);                      \
    GLL(bS + 192 * K_DIM,   ldsB + (PB) + 24576 + wvD);                      \
    bS += 64; }

  f32x4 acc[8][4];
#pragma unroll
  for (int m = 0; m < 8; ++m)
#pragma unroll
    for (int n = 0; n < 4; ++n) acc[m][n] = (f32x4){0.f, 0.f, 0.f, 0.f};

  half8 aLo[4][2], aHi[4][2], B0[2][2], B1[2][2];

#define LD_ALO(PB)                                                           \
  _Pragma("unroll") for (int fm = 0; fm < 4; ++fm)                           \
  _Pragma("unroll") for (int ks = 0; ks < 2; ++ks)                           \
    aLo[fm][ks] = *(const half8*)(pA[ks] + (PB) + fm * 2048);
#define LD_AHI(PB)                                                           \
  _Pragma("unroll") for (int fm = 0; fm < 4; ++fm)                           \
  _Pragma("unroll") for (int ks = 0; ks < 2; ++ks)                           \
    aHi[fm][ks] = *(const half8*)(pA[ks] + (PB) + 8192 + fm * 2048);
#define LD_B(REG, FNB, PB)                                                   \
  _Pragma("unroll") for (int fn = 0; fn < 2; ++fn)                           \
  _Pragma("unroll") for (int ks = 0; ks < 2; ++ks)                           \
    REG[fn][ks] = *(const half8*)(pB[ks] + (PB) + ((FNB) + fn) * 2048);
#define MQ(AH, BH, MOFF, NOFF)                                               \
  _Pragma("unroll") for (int fm = 0; fm < 4; ++fm)                           \
  _Pragma("unroll") for (int fn = 0; fn < 2; ++fn)                           \
  _Pragma("unroll") for (int ks = 0; ks < 2; ++ks)                           \
    acc[(MOFF) + fm][(NOFF) + fn] = __builtin_amdgcn_mfma_f32_16x16x32_f16(  \
        AH[fm][ks], BH[fn][ks], acc[(MOFF) + fm][(NOFF) + fn], 0, 0, 0);

  // Prologue: stage tiles 0 and 1 (16 GLL); retire tile 0 (keep tile 1 in
  // flight -> matches steady-state invariant of 8 outstanding after P3).
  STA(0); STB(0); STA(32768); STB(32768);
  VMWAIT(8); BAR();
  LD_ALO(0);          // a(0,lo)
  LD_B(B0, 0, 0);     // b(0,0)

  // RDA: read a(t+1,lo) at P2.  RDB: read b(t+1,0) at P3.  STG: stage t+2.
#define TILE(PB, RDA, RDB, STG)                                              \
  {                                                                          \
    LD_B(B1, 2, PB);                      /* P0: b(t,1)             */       \
    SP1(); MQ(aLo, B0, 0, 0); SP0();      /* Q00                    */       \
    LD_AHI(PB);                           /* P1: a(t,hi)            */       \
    SP1(); MQ(aLo, B1, 0, 2); SP0();      /* Q01 (last use of aLo)  */       \
    VMWAIT(4); BAR();                     /* publish A(t+1)         */       \
    if (RDA) LD_ALO((PB) ^ 32768);        /* P2: a(t+1,lo)          */       \
    SP1(); MQ(aHi, B1, 4, 2); SP0();      /* Q11 (last use of B1)   */       \
    VMWAIT(0); BAR();                     /* publish B(t+1)         */       \
    if (STG) { STA(PB); STB(PB); }        /* P3: {A,B}(t+2)->buf[t] */       \
    SP1(); MQ(aHi, B0, 4, 0); SP0();      /* Q10 (last use of B0)   */       \
    if (RDB) LD_B(B0, 0, (PB) ^ 32768);   /* b(t+1,0) -> B0 regs    */       \
  }

  for (int tt = 0; tt < 12; tt += 2) {
    TILE(0,     1, 1, 1);
    TILE(32768, 1, 1, 1);
  }
  TILE(0,     1, 1, 1);   // t=12 (stages 14)
  TILE(32768, 1, 1, 1);   // t=13 (stages 15)
  TILE(0,     1, 1, 0);   // t=14 (no stage; reads tile-15 frags)
  TILE(32768, 0, 0, 0);   // t=15 (compute only)

  // Epilogue: bin this block's 256x256 projections (128 values/thread).
  // torch.histc semantics: count iff min<=v<=max; v==max -> last bin.
  // Histogram params loaded here (not pre-loop) to shorten live ranges.
#pragma unroll
  for (int nf = 0; nf < 4; ++nf) {
    const int lc = wn * 64 + nf * 16 + l16;
    const float a = mins[colBase + lc], b = maxs[colBase + lc];
    const float sc = (float)NBINS / (b - a);
    int* colHist = &shist[lc * HSTRIDE];
#pragma unroll
    for (int mf = 0; mf < 8; ++mf) {
#pragma unroll
      for (int r = 0; r < 4; ++r) {
        float v = acc[mf][nf][r];
        if (v >= a && v <= b) {
          int bin = (int)((v - a) * sc);          // (v-a)>=0 -> trunc==floor
          bin = bin > NBINS - 1 ? NBINS - 1 : bin;
          atomicAdd(&colHist[bin], 1);
        }
      }
    }
  }
  __syncthreads();
  for (int i = t; i < 256 * NBINS; i += 512) {
    int col = i / NBINS, bin = i - col * NBINS;
    int v = shist[col * HSTRIDE + bin];
    if (v) atomicAdd(&ghist[colBase * NBINS + i], v);
  }
}

// ---------------- fallback (no workspace): fp32-staged 128x128 tile -------
__global__ __launch_bounds__(256) void gemm_hist_fb(
    const float* __restrict__ xf, const float* __restrict__ wf,
    const float* __restrict__ mins, const float* __restrict__ maxs,
    int* __restrict__ ghist)
{
  __shared__ __align__(16) half_t ldsA[4096];
  __shared__ __align__(16) half_t ldsB[4096];
  __shared__ int shist[128 * HSTRIDE];

  const int t     = threadIdx.x;
  const int lane  = t & 63;
  const int wv    = t >> 6;
  const int waveM = wv >> 1;
  const int waveN = wv & 1;
  const int l16   = lane & 15;
  const int quad  = lane >> 4;
  const int colBase = blockIdx.x * 128;

  for (int i = t; i < 128 * HSTRIDE; i += 256) shist[i] = 0;

  float mn[4], mx[4], inv[4];
  int lcol[4];
#pragma unroll
  for (int nt = 0; nt < 4; ++nt) {
    int lc = waveN * 64 + nt * 16 + l16;
    lcol[nt] = lc;
    float a = mins[colBase + lc], b = maxs[colBase + lc];
    mn[nt] = a; mx[nt] = b;
    inv[nt] = (float)NBINS / (b - a);
  }

  int aOff[4], bOff[4];
#pragma unroll
  for (int mt = 0; mt < 4; ++mt) {
    int m = waveM * 64 + mt * 16 + l16;
    aOff[mt] = (m * 4 + (quad ^ ((m >> 1) & 3))) * 8;
  }
#pragma unroll
  for (int nt = 0; nt < 4; ++nt) {
    int n = waveN * 64 + nt * 16 + l16;
    bOff[nt] = (n * 4 + (quad ^ ((n >> 1) & 3))) * 8;
  }

  for (int rt = blockIdx.y; rt < S_DIM / 128; rt += gridDim.y) {
    const int rowBase = rt * 128;
    f32x4 acc[4][4];
#pragma unroll
    for (int mt = 0; mt < 4; ++mt)
#pragma unroll
      for (int nt = 0; nt < 4; ++nt) acc[mt][nt] = (f32x4){0.f, 0.f, 0.f, 0.f};

    for (int kt = 0; kt < K_DIM; kt += 32) {
      __syncthreads();
#pragma unroll
      for (int i = 0; i < 2; ++i) {
        const int seg = t + i * 256;
        const int row = seg >> 2;
        const int kch = (seg & 3) ^ ((row >> 1) & 3);
        const float* ga = xf + (size_t)(rowBase + row) * K_DIM + kt + kch * 8;
        float4 v0 = ((const float4*)ga)[0];
        float4 v1 = ((const float4*)ga)[1];
        half8 h = { (half_t)v0.x, (half_t)v0.y, (half_t)v0.z, (half_t)v0.w,
                    (half_t)v1.x, (half_t)v1.y, (half_t)v1.z, (half_t)v1.w };
        *(half8*)&ldsA[seg * 8] = h;
        const float* gb = wf + (size_t)(colBase + row) * K_DIM + kt + kch * 8;
        float4 u0 = ((const float4*)gb)[0];
        float4 u1 = ((const float4*)gb)[1];
        half8 g = { (half_t)u0.x, (half_t)u0.y, (half_t)u0.z, (half_t)u0.w,
                    (half_t)u1.x, (half_t)u1.y, (half_t)u1.z, (half_t)u1.w };
        *(half8*)&ldsB[seg * 8] = g;
      }
      __syncthreads();
      {
        half8 aFf[4], bFf[4];
#pragma unroll
        for (int mt = 0; mt < 4; ++mt) aFf[mt] = *(const half8*)&ldsA[aOff[mt]];
#pragma unroll
        for (int nt = 0; nt < 4; ++nt) bFf[nt] = *(const half8*)&ldsB[bOff[nt]];
#pragma unroll
        for (int mt = 0; mt < 4; ++mt)
#pragma unroll
          for (int nt = 0; nt < 4; ++nt)
            acc[mt][nt] = __builtin_amdgcn_mfma_f32_16x16x32_f16(
                aFf[mt], bFf[nt], acc[mt][nt], 0, 0, 0);
      }
    }

#pragma unroll
    for (int nt = 0; nt < 4; ++nt) {
      const float a = mn[nt], b = mx[nt], sc = inv[nt];
      int* colHist = &shist[lcol[nt] * HSTRIDE];
#pragma unroll
      for (int mt = 0; mt < 4; ++mt) {
#pragma unroll
        for (int r = 0; r < 4; ++r) {
          float v = acc[mt][nt][r];
          if (v >= a && v <= b) {
            int bin = (int)((v - a) * sc);
            bin = bin > NBINS - 1 ? NBINS - 1 : bin;
            atomicAdd(&colHist[bin], 1);
          }
        }
      }
    }
  }

  __syncthreads();
  for (int i = t; i < 128 * NBINS; i += 256) {
    int col = i / NBINS, bin = i - col * NBINS;
    int v = shist[col * HSTRIDE + bin];
    if (v) atomicAdd(&ghist[colBase * NBINS + i], v);
  }
}

// ---------------- L2 normalize per group of 20 bins (in place) ------------
__global__ void normalize_kernel(const int* __restrict__ hist, float* __restrict__ out) {
  int g = blockIdx.x * blockDim.x + threadIdx.x;
  if (g >= D_DIM) return;
  const int base = g * NBINS;
  float v[NBINS];
  float ss = 0.f;
#pragma unroll
  for (int i = 0; i < NBINS; ++i) { v[i] = (float)hist[base + i]; ss += v[i] * v[i]; }
  float sc = 1.0f / fmaxf(sqrtf(ss), 1e-12f);
#pragma unroll
  for (int i = 0; i < NBINS; ++i) out[base + i] = v[i] * sc;
}

extern "C" void kernel_launch(void* const* d_in, const int* in_sizes, int n_in,
                              void* d_out, int out_size, void* d_ws, size_t ws_size,
                              hipStream_t stream) {
  const float* x    = (const float*)d_in[0];
  const float* W    = (const float*)d_in[1];
  const float* mins = (const float*)d_in[2];
  const float* maxs = (const float*)d_in[3];
  float* out = (float*)d_out;

  const size_t xh_elems = (size_t)S_DIM * K_DIM;
  const size_t wh_elems = (size_t)D_DIM * K_DIM;
  const size_t need = (xh_elems + wh_elems) * sizeof(half_t);

  if (ws_size >= need) {
    half_t* xh = (half_t*)d_ws;
    half_t* wh = xh + xh_elems;
    int n8x = (int)(xh_elems / 8), n8w = (int)(wh_elems / 8);
    int tot = n8x + n8w;
    // cvt also zeroes d_out (re-poisoned 0xAA between runs)
    cvt_f32_f16<<<(tot + 255) / 256, 256, 0, stream>>>(
        x, xh, n8x, W, wh, n8w, (float4*)d_out, out_size / 4);
    gemm_hist256<<<dim3(1600), 512, 0, stream>>>(xh, wh, mins, maxs, (int*)d_out);
  } else {
    hipMemsetAsync(d_out, 0, (size_t)out_size * sizeof(float), stream);
    gemm_hist_fb<<<dim3(D_DIM / 128, 64), 256, 0, stream>>>(
        x, W, mins, maxs, (int*)d_out);
  }

  normalize_kernel<<<(D_DIM + 255) / 256, 256, 0, stream>>>((int*)d_out, out);
}